// Round 1
// baseline (337.686 us; speedup 1.0000x reference)
//
#include <hip/hip_runtime.h>
#include <hip/hip_bf16.h>

typedef __attribute__((ext_vector_type(8))) short bf16x8;   // 8 bf16 = 4 VGPR (MFMA A/B frag)
typedef __attribute__((ext_vector_type(4))) float f32x4;    // MFMA C/D frag
typedef unsigned int u32;
typedef unsigned short u16;

#define B_ 4
#define T_ 4096
#define D_ 512
#define KVBLK 32
#define QBLK 64

// LDS layout (bytes)
#define K_OFF   0        // [32][512] bf16, 16B-granule XOR-swizzle by (kv&7)
#define VT_OFF  32768    // [512][32] bf16 (V transposed), swizzle by ((d>>1)&3)
#define S_OFF   65536    // [64][32] f32 logits
#define P_OFF   73728    // [64][64] bf16 rows (128B stride, 32 kv used), swizzle (q&7)
#define SC_OFF  81920    // 64 f32 row rescale factors
#define L_OFF   82176    // 64 f32 row denominators
#define F_OFF   82432    // int rescale flag
#define LDS_BYTES 82448

#define LOG2E 1.44269504088896f

__device__ __forceinline__ u16 f2bf(float f) {  // RNE f32->bf16 (inputs finite)
  u32 u = __float_as_uint(f);
  u += 0x7fffu + ((u >> 16) & 1u);
  return (u16)(u >> 16);
}

__device__ __forceinline__ void gload16(const void* g, void* l) {
  __builtin_amdgcn_global_load_lds((const __attribute__((address_space(1))) u32*)g,
                                   (__attribute__((address_space(3))) u32*)l, 16, 0, 0);
}

// Convert x (f32) -> x_bf16 row-major AND x^T bf16 (d-major), per batch.
// 64x64 tiles through LDS so both global writes are coalesced.
__global__ __launch_bounds__(256) void prep_kernel(const float* __restrict__ x,
                                                   u16* __restrict__ xws,
                                                   u16* __restrict__ xt) {
  __shared__ u16 tile[64][65];
  int bid = blockIdx.x;            // B * (T/64) * (D/64) = 4*64*8 = 2048
  int b = bid >> 9;
  int rem = bid & 511;
  int t0 = (rem >> 3) << 6;
  int d0 = (rem & 7) << 6;
  int tid = threadIdx.x;
  int i = tid >> 2;                // tile row 0..63
  int jg = tid & 3;                // 16-col group
  union { u16 h[16]; uint4 q[2]; } vv;
  const float* src = x + ((size_t)(b * T_ + t0 + i)) * D_ + d0 + jg * 16;
#pragma unroll
  for (int k = 0; k < 4; ++k) {
    float4 v = *(const float4*)(src + k * 4);
    vv.h[k * 4 + 0] = f2bf(v.x); vv.h[k * 4 + 1] = f2bf(v.y);
    vv.h[k * 4 + 2] = f2bf(v.z); vv.h[k * 4 + 3] = f2bf(v.w);
  }
  u16* dst = xws + ((size_t)(b * T_ + t0 + i)) * D_ + d0 + jg * 16;
  *(uint4*)(dst) = vv.q[0];
  *(uint4*)(dst + 8) = vv.q[1];
#pragma unroll
  for (int k = 0; k < 16; ++k) tile[i][jg * 16 + k] = vv.h[k];
  __syncthreads();
  int jj = tid >> 2;               // d-row within tile
  int tg = tid & 3;                // 16-t group
  union { u16 h[16]; uint4 q[2]; } ov;
#pragma unroll
  for (int mm = 0; mm < 16; ++mm) ov.h[mm] = tile[tg * 16 + mm][jj];
  u16* dstT = xt + ((size_t)(b * D_ + d0 + jj)) * T_ + t0 + tg * 16;
  *(uint4*)(dstT) = ov.q[0];
  *(uint4*)(dstT + 8) = ov.q[1];
}

// Flash attention. Block = (batch b, 64 q-rows). 8 waves.
// Warp qtile=wid&3 holds Q rows qtile*16+lane15 fully in regs (64 VGPR).
// QK^T: warp (qtile=wid&3, kvtile=wid>>2) computes one 16x16 S tile, k=512.
// PV:   warp wid owns d-chunk [wid*64, wid*64+64): 4x4 tiles, k=32.
__global__ __launch_bounds__(512, 2) void attn_kernel(const u16* __restrict__ xws,
                                                      const u16* __restrict__ xt,
                                                      float* __restrict__ out) {
  extern __shared__ char smem[];
  const int tid = threadIdx.x;
  const int wid = tid >> 6;
  const int lane = tid & 63;
  const int g = lane >> 4;
  const int l15 = lane & 15;
  const int bid = blockIdx.x;
  const int b = bid & 3;           // XCD x serves batch x&3 only (L2 affinity)
  const int q0 = (bid >> 2) * QBLK;

  const int qtile = wid & 3;
  const int kvtile = wid >> 2;

  // Q fragments in registers: a_frag[ks][j] = Q[q0+qtile*16+l15][ks*32 + g*8 + j]
  bf16x8 qreg[16];
  {
    const u16* qbase = xws + ((size_t)(b * T_ + q0 + qtile * 16 + l15)) * D_;
#pragma unroll
    for (int ks = 0; ks < 16; ++ks)
      qreg[ks] = *(const bf16x8*)(qbase + ks * 32 + g * 8);
  }

  f32x4 acc[4][4];
#pragma unroll
  for (int i = 0; i < 4; ++i)
#pragma unroll
    for (int j = 0; j < 4; ++j)
      acc[i][j] = (f32x4){0.f, 0.f, 0.f, 0.f};

  float m = -1e30f, lden = 0.f;    // online-softmax state; 8 identical copies/row
  const int sq = tid >> 3;         // softmax row 0..63
  const int sub = tid & 7;         // 8 lanes per row

  for (int it = 0; it < T_ / KVBLK; ++it) {
    const int kv0 = it * KVBLK;
    __syncthreads();   // A: prev PV done reading Vt/P, prev QK done reading K

    // ---- stage K rows (row-major, granule pre-swizzled source) ----
#pragma unroll
    for (int i = 0; i < 4; ++i) {
      int kvl = wid * 4 + i;
      const char* src = (const char*)(xws + ((size_t)(b * T_ + kv0 + kvl)) * D_);
      gload16(src + ((lane ^ (kvl & 7)) << 4), smem + K_OFF + kvl * 1024);
    }
    // ---- stage V^T rows (16 d-rows of 64B per wave-inst) ----
#pragma unroll
    for (int i = 0; i < 4; ++i) {
      int d0r = wid * 64 + i * 16;
      int d = d0r + (lane >> 2);
      const char* src = (const char*)(xt + ((size_t)(b * D_ + d)) * T_ + kv0);
      gload16(src + (((lane & 3) ^ ((d >> 1) & 3)) << 4), smem + VT_OFF + d0r * 64);
    }
    if (tid == 0) *(int*)(smem + F_OFF) = 0;
    asm volatile("s_waitcnt vmcnt(0)" ::: "memory");
    __syncthreads();   // B: tiles ready

    // ---- QK^T: one 16x16 tile per warp, two independent chains ----
    f32x4 s0 = (f32x4){0.f, 0.f, 0.f, 0.f}, s1 = (f32x4){0.f, 0.f, 0.f, 0.f};
    const int kvrow = kvtile * 16 + l15;
    const int ksw = (kvrow & 7) << 4;
#pragma unroll
    for (int ks = 0; ks < 16; ks += 2) {
      bf16x8 b0 = *(const bf16x8*)(smem + K_OFF + kvrow * 1024 + ((ks * 64 + g * 16) ^ ksw));
      bf16x8 b1 = *(const bf16x8*)(smem + K_OFF + kvrow * 1024 + (((ks + 1) * 64 + g * 16) ^ ksw));
      s0 = __builtin_amdgcn_mfma_f32_16x16x32_bf16(qreg[ks], b0, s0, 0, 0, 0);
      s1 = __builtin_amdgcn_mfma_f32_16x16x32_bf16(qreg[ks + 1], b1, s1, 0, 0, 0);
    }
    s0 += s1;
#pragma unroll
    for (int r = 0; r < 4; ++r)
      *(float*)(smem + S_OFF + (qtile * 16 + g * 4 + r) * 128 + (kvtile * 16 + l15) * 4) = s0[r];
    __syncthreads();   // C: S complete

    // ---- softmax (row sq, cols sub*4..sub*4+3), defer-max THR=8 ----
    f32x4 sv = *(const f32x4*)(smem + S_OFF + sq * 128 + sub * 16);
    float tmax = fmaxf(fmaxf(sv.x, sv.y), fmaxf(sv.z, sv.w));
    tmax = fmaxf(tmax, __shfl_xor(tmax, 1));
    tmax = fmaxf(tmax, __shfl_xor(tmax, 2));
    tmax = fmaxf(tmax, __shfl_xor(tmax, 4));
    float scl = 1.f;
    if (tmax > m + 8.f) {
      scl = exp2f((m - tmax) * LOG2E);
      m = tmax;
      *(int*)(smem + F_OFF) = 1;   // benign same-value race
    }
    if (sub == 0) *(float*)(smem + SC_OFF + sq * 4) = scl;
    float p0 = exp2f((sv.x - m) * LOG2E);
    float p1 = exp2f((sv.y - m) * LOG2E);
    float p2 = exp2f((sv.z - m) * LOG2E);
    float p3 = exp2f((sv.w - m) * LOG2E);
    float psum = (p0 + p1) + (p2 + p3);
    psum += __shfl_xor(psum, 1);
    psum += __shfl_xor(psum, 2);
    psum += __shfl_xor(psum, 4);
    lden = lden * scl + psum;
    uint2 pw;
    pw.x = (u32)f2bf(p0) | ((u32)f2bf(p1) << 16);
    pw.y = (u32)f2bf(p2) | ((u32)f2bf(p3) << 16);
    *(uint2*)(smem + P_OFF + sq * 128 + ((sub * 8) ^ ((sq & 7) << 4))) = pw;
    __syncthreads();   // D: P/scale ready

    // ---- rescale O only when some row's max moved (rare: ~2x per row) ----
    if (*(const int*)(smem + F_OFF)) {
#pragma unroll
      for (int rt = 0; rt < 4; ++rt) {
        f32x4 sc;
#pragma unroll
        for (int r = 0; r < 4; ++r)
          sc[r] = *(const float*)(smem + SC_OFF + (rt * 16 + g * 4 + r) * 4);
#pragma unroll
        for (int ct = 0; ct < 4; ++ct)
          acc[rt][ct] *= sc;
      }
    }
    // ---- PV: 4x4 tiles, k=32 ----
    bf16x8 bfr[4];
#pragma unroll
    for (int ct = 0; ct < 4; ++ct) {
      int d = wid * 64 + ct * 16 + l15;
      bfr[ct] = *(const bf16x8*)(smem + VT_OFF + d * 64 + ((g * 16) ^ (((d >> 1) & 3) << 4)));
    }
#pragma unroll
    for (int rt = 0; rt < 4; ++rt) {
      int q = rt * 16 + l15;
      bf16x8 af = *(const bf16x8*)(smem + P_OFF + q * 128 + ((g * 16) ^ ((q & 7) << 4)));
#pragma unroll
      for (int ct = 0; ct < 4; ++ct)
        acc[rt][ct] = __builtin_amdgcn_mfma_f32_16x16x32_bf16(af, bfr[ct], acc[rt][ct], 0, 0, 0);
    }
  }

  // ---- epilogue: y = acc / l ----
  if (sub == 0) *(float*)(smem + L_OFF + sq * 4) = lden;
  __syncthreads();
#pragma unroll
  for (int rt = 0; rt < 4; ++rt) {
#pragma unroll
    for (int r = 0; r < 4; ++r) {
      int row = rt * 16 + g * 4 + r;
      float inv = 1.0f / *(const float*)(smem + L_OFF + row * 4);
      size_t obase = ((size_t)(b * T_ + q0 + row)) * D_ + wid * 64;
#pragma unroll
      for (int ct = 0; ct < 4; ++ct)
        out[obase + ct * 16 + l15] = acc[rt][ct][r] * inv;
    }
  }
}

extern "C" void kernel_launch(void* const* d_in, const int* in_sizes, int n_in,
                              void* d_out, int out_size, void* d_ws, size_t ws_size,
                              hipStream_t stream) {
  const float* x = (const float*)d_in[0];
  float* out = (float*)d_out;
  u16* xws = (u16*)d_ws;                       // bf16 x, 16 MB
  u16* xt = xws + (size_t)B_ * T_ * D_;        // bf16 x^T, 16 MB  (needs ws >= 32 MB)
  (void)in_sizes; (void)n_in; (void)out_size; (void)ws_size;

  hipFuncSetAttribute((const void*)attn_kernel,
                      hipFuncAttributeMaxDynamicSharedMemorySize, LDS_BYTES);

  prep_kernel<<<dim3(2048), dim3(256), 0, stream>>>(x, xws, xt);
  attn_kernel<<<dim3(256), dim3(512), LDS_BYTES, stream>>>(xws, xt, out);
}

// Round 2
// 240.616 us; speedup vs baseline: 1.4034x; 1.4034x over previous
//
#include <hip/hip_runtime.h>
#include <hip/hip_bf16.h>

typedef __attribute__((ext_vector_type(8))) short bf16x8;   // 8 bf16 = 4 VGPR (MFMA A/B frag)
typedef __attribute__((ext_vector_type(4))) float f32x4;    // MFMA C/D frag
typedef unsigned int u32;
typedef unsigned short u16;

#define B_ 4
#define T_ 4096
#define D_ 512
#define KVBLK 32
#define QBLK 64
#define NIT (T_ / KVBLK)

// LDS layout (bytes)
#define K_OFF   0                    // 2 x [32 kv][512 d] bf16, 16B-granule XOR swizzle by (kv&7)
#define KBUF    32768
#define P_OFF   65536                // [64 q] rows, 80B stride (64B data + 16B pad)
#define PSTR    80
#define M_OFF   (P_OFF + 64*PSTR)    // 64 f32: per-row fixed softmax shift (row norm)
#define L_OFF   (M_OFF + 256)        // 64 f32: denominators
#define LDS_BYTES (L_OFF + 256)      // 71168 B -> 1 block/CU

#define LOG2E 1.44269504088896f

__device__ __forceinline__ u16 f2bf(float f) {  // RNE f32->bf16 (inputs finite, positive here)
  u32 u = __float_as_uint(f);
  u += 0x7fffu + ((u >> 16) & 1u);
  return (u16)(u >> 16);
}

__device__ __forceinline__ float bf2f(short s) {
  return __uint_as_float(((u32)(u16)s) << 16);
}

__device__ __forceinline__ void gload16(const void* g, void* l) {
  __builtin_amdgcn_global_load_lds((const __attribute__((address_space(1))) u32*)g,
                                   (__attribute__((address_space(3))) u32*)l, 16, 0, 0);
}

// x (f32) -> x_bf16 row-major AND x^T bf16 (d-major). 64x64 tiles via LDS.
__global__ __launch_bounds__(256) void prep_kernel(const float* __restrict__ x,
                                                   u16* __restrict__ xws,
                                                   u16* __restrict__ xt) {
  __shared__ u16 tile[64][65];
  int bid = blockIdx.x;            // 4*64*8 = 2048
  int b = bid >> 9;
  int rem = bid & 511;
  int t0 = (rem >> 3) << 6;
  int d0 = (rem & 7) << 6;
  int tid = threadIdx.x;
  int i = tid >> 2;
  int jg = tid & 3;
  union { u16 h[16]; uint4 q[2]; } vv;
  const float* src = x + ((size_t)(b * T_ + t0 + i)) * D_ + d0 + jg * 16;
#pragma unroll
  for (int k = 0; k < 4; ++k) {
    float4 v = *(const float4*)(src + k * 4);
    vv.h[k * 4 + 0] = f2bf(v.x); vv.h[k * 4 + 1] = f2bf(v.y);
    vv.h[k * 4 + 2] = f2bf(v.z); vv.h[k * 4 + 3] = f2bf(v.w);
  }
  u16* dst = xws + ((size_t)(b * T_ + t0 + i)) * D_ + d0 + jg * 16;
  *(uint4*)(dst) = vv.q[0];
  *(uint4*)(dst + 8) = vv.q[1];
#pragma unroll
  for (int k = 0; k < 16; ++k) tile[i][jg * 16 + k] = vv.h[k];
  __syncthreads();
  int jj = tid >> 2;
  int tg = tid & 3;
  union { u16 h[16]; uint4 q[2]; } ov;
#pragma unroll
  for (int mm = 0; mm < 16; ++mm) ov.h[mm] = tile[tg * 16 + mm][jj];
  u16* dstT = xt + ((size_t)(b * D_ + d0 + jj)) * T_ + t0 + tg * 16;
  *(uint4*)(dstT) = ov.q[0];
  *(uint4*)(dstT + 8) = ov.q[1];
}

// Flash attention, fixed-m softmax (shift-invariance: exact for any per-row m
// as long as exp doesn't overflow; m = row norm == diagonal logit).
// Block = (batch, 64 q rows), 8 waves. QK: warp (qtile=wid&3, kvtile=wid>>2)
// does one 16x16 S-tile over k=512. PV: warp wid owns d-chunk [wid*64, +64).
// K double-buffered in LDS (global_load_lds, issued one iter ahead);
// V^T read global->reg (issued top of iter, consumed in PV after barrier).
__global__ __launch_bounds__(512, 1) void attn_kernel(const u16* __restrict__ xws,
                                                      const u16* __restrict__ xt,
                                                      float* __restrict__ out) {
  extern __shared__ char smem[];
  const int tid = threadIdx.x;
  const int wid = tid >> 6;
  const int lane = tid & 63;
  const int g = lane >> 4;
  const int l15 = lane & 15;
  const int bid = blockIdx.x;
  const int b = bid & 3;           // XCD L2 affinity: one batch per XCD group
  const int q0 = (bid >> 2) * QBLK;

  const int qtile = wid & 3;
  const int kvtile = wid >> 2;

  // ---- Q fragments in registers: qreg[ks] = Q[qtile*16+l15][ks*32+g*8 ..+8]
  bf16x8 qreg[16];
  {
    const u16* qbase = xws + ((size_t)(b * T_ + q0 + qtile * 16 + l15)) * D_;
#pragma unroll
    for (int ks = 0; ks < 16; ++ks)
      qreg[ks] = *(const bf16x8*)(qbase + ks * 32 + g * 8);
  }

  // ---- prologue: row norms -> m (fixed softmax shift), stage K tile 0
  {
    float nrm = 0.f;
#pragma unroll
    for (int ks = 0; ks < 16; ++ks)
#pragma unroll
      for (int j = 0; j < 8; ++j) {
        float v = bf2f(qreg[ks][j]);
        nrm = fmaf(v, v, nrm);
      }
    nrm += __shfl_xor(nrm, 16);
    nrm += __shfl_xor(nrm, 32);
    if (wid < 4 && lane < 16)
      *(float*)(smem + M_OFF + (qtile * 16 + l15) * 4) = nrm;
  }
#pragma unroll
  for (int i = 0; i < 4; ++i) {
    int kvl = wid * 4 + i;
    const char* src = (const char*)(xws + ((size_t)(b * T_) + kvl) * D_);
    gload16(src + ((lane ^ (kvl & 7)) << 4), smem + K_OFF + kvl * 1024);
  }
  __syncthreads();   // m visible + K0 ordering (full drain once is fine)
  asm volatile("s_waitcnt vmcnt(0)" ::: "memory");
  __builtin_amdgcn_s_barrier();

  // mlog[r] = m * LOG2E for rows qtile*16+g*4+r  (exp arg = s*LOG2E - mlog)
  float mlog[4];
#pragma unroll
  for (int r = 0; r < 4; ++r)
    mlog[r] = *(const float*)(smem + M_OFF + (qtile * 16 + g * 4 + r) * 4) * LOG2E;

  f32x4 acc[4][4];
#pragma unroll
  for (int i = 0; i < 4; ++i)
#pragma unroll
    for (int j = 0; j < 4; ++j)
      acc[i][j] = (f32x4){0.f, 0.f, 0.f, 0.f};
  f32x4 lsum = (f32x4){0.f, 0.f, 0.f, 0.f};

  const char* krow0 = smem + K_OFF + (kvtile * 16 + l15) * 1024;  // + cur*KBUF
  const int ksw = (l15 & 7) << 4;
  char* const pwr = smem + P_OFF + (qtile * 16 + g * 4) * PSTR + (kvtile * 16 + l15) * 2;
  const char* const prd = smem + P_OFF + l15 * PSTR + g * 16;     // + rt*16*PSTR
  const u16* const vbase = xt + ((size_t)(b * D_ + wid * 64 + l15)) * T_ + g * 8;

  for (int it = 0; it < NIT; ++it) {
    const int cur = it & 1;

    // ---- V^T direct global->reg, issued FIRST (compiler wait = vmcnt(4)) ----
    bf16x8 bfr[4];
#pragma unroll
    for (int ct = 0; ct < 4; ++ct)
      bfr[ct] = *(const bf16x8*)(vbase + (size_t)ct * 16 * T_ + it * KVBLK);

    // ---- stage next K tile into the other buffer (no wait here) ----
    if (it + 1 < NIT) {
      char* nk = smem + K_OFF + (cur ^ 1) * KBUF;
#pragma unroll
      for (int i = 0; i < 4; ++i) {
        int kvl = wid * 4 + i;
        const char* src = (const char*)(xws + ((size_t)(b * T_) + (size_t)(it + 1) * KVBLK + kvl) * D_);
        gload16(src + ((lane ^ (kvl & 7)) << 4), nk + kvl * 1024);
      }
    }

    // ---- QK^T: 16 MFMA, 4 independent chains ----
    const char* krow = krow0 + cur * KBUF;
    f32x4 s0 = (f32x4){0.f,0.f,0.f,0.f}, s1 = s0, s2 = s0, s3 = s0;
#pragma unroll
    for (int ks = 0; ks < 16; ks += 4) {
      bf16x8 k0 = *(const bf16x8*)(krow + (((ks + 0) * 64 + g * 16) ^ ksw));
      bf16x8 k1 = *(const bf16x8*)(krow + (((ks + 1) * 64 + g * 16) ^ ksw));
      bf16x8 k2 = *(const bf16x8*)(krow + (((ks + 2) * 64 + g * 16) ^ ksw));
      bf16x8 k3 = *(const bf16x8*)(krow + (((ks + 3) * 64 + g * 16) ^ ksw));
      s0 = __builtin_amdgcn_mfma_f32_16x16x32_bf16(qreg[ks + 0], k0, s0, 0, 0, 0);
      s1 = __builtin_amdgcn_mfma_f32_16x16x32_bf16(qreg[ks + 1], k1, s1, 0, 0, 0);
      s2 = __builtin_amdgcn_mfma_f32_16x16x32_bf16(qreg[ks + 2], k2, s2, 0, 0, 0);
      s3 = __builtin_amdgcn_mfma_f32_16x16x32_bf16(qreg[ks + 3], k3, s3, 0, 0, 0);
    }
    s0 = (s0 + s1) + (s2 + s3);

    // ---- elementwise softmax numerator + P write (bf16) ----
#pragma unroll
    for (int r = 0; r < 4; ++r) {
      float p = exp2f(fmaf(s0[r], LOG2E, -mlog[r]));
      lsum[r] += p;
      *(u16*)(pwr + r * PSTR) = f2bf(p);
    }

    // ---- barrier E: P visible; staged loads stay in flight ----
    asm volatile("s_waitcnt lgkmcnt(0)" ::: "memory");
    __builtin_amdgcn_sched_barrier(0);
    __builtin_amdgcn_s_barrier();

    // ---- PV: 16 MFMA (4x4 tiles), A = P frags, B = bfr ----
#pragma unroll
    for (int rt = 0; rt < 4; ++rt) {
      bf16x8 af = *(const bf16x8*)(prd + rt * 16 * PSTR);
#pragma unroll
      for (int ct = 0; ct < 4; ++ct)
        acc[rt][ct] = __builtin_amdgcn_mfma_f32_16x16x32_bf16(af, bfr[ct], acc[rt][ct], 0, 0, 0);
    }

    // ---- barrier F: all reads of buf[cur]/P done; next-K staged loads landed ----
    asm volatile("s_waitcnt vmcnt(0)" ::: "memory");
    __builtin_amdgcn_sched_barrier(0);
    __builtin_amdgcn_s_barrier();
  }

  // ---- epilogue: denominators (reduce lsum over l15, then across kvtile pair) ----
  {
#pragma unroll
    for (int r = 0; r < 4; ++r) {
      lsum[r] += __shfl_xor(lsum[r], 1);
      lsum[r] += __shfl_xor(lsum[r], 2);
      lsum[r] += __shfl_xor(lsum[r], 4);
      lsum[r] += __shfl_xor(lsum[r], 8);
    }
    if (kvtile == 0 && l15 == 0)
#pragma unroll
      for (int r = 0; r < 4; ++r)
        *(float*)(smem + L_OFF + (qtile * 16 + g * 4 + r) * 4) = lsum[r];
    __syncthreads();
    if (kvtile == 1 && l15 == 0)
#pragma unroll
      for (int r = 0; r < 4; ++r)
        *(float*)(smem + L_OFF + (qtile * 16 + g * 4 + r) * 4) += lsum[r];
    __syncthreads();
  }

  // ---- output: y = acc / L ----
#pragma unroll
  for (int rt = 0; rt < 4; ++rt) {
#pragma unroll
    for (int r = 0; r < 4; ++r) {
      int row = rt * 16 + g * 4 + r;
      float inv = 1.0f / *(const float*)(smem + L_OFF + row * 4);
      size_t obase = ((size_t)(b * T_ + q0 + row)) * D_ + wid * 64;
#pragma unroll
      for (int ct = 0; ct < 4; ++ct)
        out[obase + ct * 16 + l15] = acc[rt][ct][r] * inv;
    }
  }
}

extern "C" void kernel_launch(void* const* d_in, const int* in_sizes, int n_in,
                              void* d_out, int out_size, void* d_ws, size_t ws_size,
                              hipStream_t stream) {
  const float* x = (const float*)d_in[0];
  float* out = (float*)d_out;
  u16* xws = (u16*)d_ws;                       // bf16 x, 16 MB
  u16* xt = xws + (size_t)B_ * T_ * D_;        // bf16 x^T, 16 MB
  (void)in_sizes; (void)n_in; (void)out_size; (void)ws_size;

  hipFuncSetAttribute((const void*)attn_kernel,
                      hipFuncAttributeMaxDynamicSharedMemorySize, LDS_BYTES);

  prep_kernel<<<dim3(2048), dim3(256), 0, stream>>>(x, xws, xt);
  attn_kernel<<<dim3(256), dim3(512), LDS_BYTES, stream>>>(xws, xt, out);
}